// Round 5
// baseline (467.960 us; speedup 1.0000x reference)
//
#include <hip/hip_runtime.h>

typedef __attribute__((ext_vector_type(8))) short short8;
typedef __attribute__((ext_vector_type(4))) float f32x4;

#define MFMA16(a, b, c) __builtin_amdgcn_mfma_f32_16x16x32_bf16((a), (b), (c), 0, 0, 0)

// raw barrier: LDS visibility only, leave vmcnt (global prefetches) in flight
#define BAR() do { asm volatile("s_waitcnt lgkmcnt(0)" ::: "memory"); \
                   __builtin_amdgcn_s_barrier(); \
                   asm volatile("" ::: "memory"); } while (0)

template<int CTRL>
__device__ __forceinline__ float dpp_ror(float x) {
  return __builtin_bit_cast(float,
      __builtin_amdgcn_update_dpp(0, __builtin_bit_cast(int, x), CTRL, 0xF, 0xF, false));
}

__device__ __forceinline__ unsigned cvtpk(float lo, float hi) {
  unsigned r;
  asm("v_cvt_pk_bf16_f32 %0, %1, %2" : "=v"(r) : "v"(lo), "v"(hi));
  return r;
}

__device__ __forceinline__ unsigned short f2b(float f) {
  union { float f; unsigned u; } v; v.f = f;
  return (unsigned short)((v.u + 0x7FFFu + ((v.u >> 16) & 1u)) >> 16);  // RNE
}

// ---------------- prep kernels ----------------
__global__ void prep_wqkv(const float* __restrict__ qkv_w, unsigned short* __restrict__ wq) {
  int idx = blockIdx.x * 256 + threadIdx.x;   // 768*256
  int wcol = idx >> 8, k = idx & 255;
  float v = qkv_w[k * 768 + wcol];
  if (wcol < 256) v *= 0.125f;
  wq[idx] = f2b(v);
}

__global__ void prep_wproj(const float* __restrict__ proj_w, unsigned short* __restrict__ wp) {
  int idx = blockIdx.x * 256 + threadIdx.x;   // 256*256
  int col = idx >> 8, k = idx & 255;
  wp[idx] = f2b(proj_w[k * 256 + col]);
}

// comb[w][h][i][j] (64x4x64x64 f32): mask+bias valid, 0 for pad rows, -1e30 for pad cols
__global__ void prep_comb(const float* __restrict__ mask, const float* __restrict__ bias_table,
                          const int* __restrict__ rel_index, float* __restrict__ comb) {
  int idx = blockIdx.x * 256 + threadIdx.x;   // 1048576
  int j = idx & 63, i = (idx >> 6) & 63, h = (idx >> 12) & 3, w = idx >> 14;
  float v;
  if (j >= 49) v = -1e30f;
  else if (i >= 49) v = 0.f;
  else v = mask[(w * 49 + i) * 49 + j] + bias_table[rel_index[i * 49 + j] * 4 + h];
  comb[idx] = v;
}

// ---------------- fused window-attention kernel ----------------
// LDS (ushort units), exact strides + XOR swizzle; 49664 B -> 3 blocks/CU.
#define XS   0        // [48][256] x bf16 rows 0-47; later O rows 0-47
#define XR   12288    // [256]     x row 48; later O row 48
#define QPS  12544    // [64][64]  Q, later aliased by P (safe: per-wave row slices)
#define KS   16640    // [64][64]  K
#define VT   20736    // [64][64]  V transposed: [dim][token]
#define LDS_TOT 24832 // ushorts = 49664 B

__device__ __forceinline__ int xsw(int row, int col) { return row * 256 + (col ^ ((row & 7) << 3)); }
__device__ __forceinline__ int tsw(int row, int col) { return row * 64  + (col ^ ((row & 7) << 3)); }

__global__ __launch_bounds__(256, 3) void win_attn(
    const float* __restrict__ x, const float* __restrict__ qkv_b,
    const float* __restrict__ proj_b, const unsigned short* __restrict__ wq,
    const unsigned short* __restrict__ wp, const float* __restrict__ comb,
    float* __restrict__ out)
{
  __shared__ alignas(16) unsigned short lds[LDS_TOT];
  const int b = blockIdx.x, tid = threadIdx.x;
  const int wv = tid >> 6, l = tid & 63, g = l >> 4, c = l & 15;

  // ---- Phase A: stage x[b] rows 0-47 -> XS (swizzled), row 48 -> XR ----
  {
    const float* xb = x + (size_t)b * (49 * 256);
    #pragma unroll
    for (int it = 0; it < 6; ++it) {
      int idx = tid + it * 256, row = idx >> 5, c8 = idx & 31;   // rows 0..47
      const f32x4* p = (const f32x4*)(xb + row * 256 + c8 * 8);
      f32x4 v0 = __builtin_nontemporal_load(p);
      f32x4 v1 = __builtin_nontemporal_load(p + 1);
      uint4 pk = make_uint4(cvtpk(v0.x, v0.y), cvtpk(v0.z, v0.w),
                            cvtpk(v1.x, v1.y), cvtpk(v1.z, v1.w));
      *(uint4*)&lds[XS + xsw(row, c8 * 8)] = pk;
    }
    if (tid < 32) {
      const f32x4* p = (const f32x4*)(xb + 48 * 256 + tid * 8);
      f32x4 v0 = __builtin_nontemporal_load(p);
      f32x4 v1 = __builtin_nontemporal_load(p + 1);
      uint4 pk = make_uint4(cvtpk(v0.x, v0.y), cvtpk(v0.z, v0.w),
                            cvtpk(v1.x, v1.y), cvtpk(v1.z, v1.w));
      *(uint4*)&lds[XR + tid * 8] = pk;
    }
  }
  BAR();

  const f32x4 zero4 = {0.f, 0.f, 0.f, 0.f};
  f32x4 oacc[4][4];
  #pragma unroll
  for (int h = 0; h < 4; ++h)
    #pragma unroll
    for (int nd = 0; nd < 4; ++nd) oacc[h][nd] = zero4;

  #pragma unroll
  for (int h = 0; h < 4; ++h) {
    // ---- comb prefetch for THIS head, issued ~2k cycles before use in B3 ----
    const float* cb = comb + (((size_t)(b & 63)) * 4 + h) * 4096;
    float cbv[4][4];
    #pragma unroll
    for (int ni = 0; ni < 4; ++ni)
      #pragma unroll
      for (int r = 0; r < 4; ++r)
        cbv[ni][r] = cb[(wv * 16 + g * 4 + r) * 64 + ni * 16 + c];

    // ---- B1: QKV GEMM for head h; wave computes 16-col slice of Q,K,V ----
    f32x4 acc[3][4];
    #pragma unroll
    for (int dst = 0; dst < 3; ++dst)
      #pragma unroll
      for (int mi = 0; mi < 4; ++mi) acc[dst][mi] = zero4;

    const unsigned short* wbase = wq + ((size_t)(h * 64 + wv * 16 + c)) * 256 + g * 8;
    short8 wf0 = *(const short8*)(wbase);
    short8 wf1 = *(const short8*)(wbase + 65536);
    short8 wf2 = *(const short8*)(wbase + 131072);
    #pragma unroll
    for (int ks = 0; ks < 8; ++ks) {
      short8 nx0, nx1, nx2;
      if (ks < 7) {                        // 1-step lookahead: loads issued before MFMAs
        nx0 = *(const short8*)(wbase + (ks + 1) * 32);
        nx1 = *(const short8*)(wbase + 65536 + (ks + 1) * 32);
        nx2 = *(const short8*)(wbase + 131072 + (ks + 1) * 32);
      }
      short8 a0 = *(const short8*)&lds[XS + xsw(0 * 16 + c, ks * 32 + g * 8)];
      short8 a1 = *(const short8*)&lds[XS + xsw(1 * 16 + c, ks * 32 + g * 8)];
      short8 a2 = *(const short8*)&lds[XS + xsw(2 * 16 + c, ks * 32 + g * 8)];
      short8 a3 = *(const short8*)&lds[XR + ks * 32 + g * 8];   // broadcast row 48
      __builtin_amdgcn_s_setprio(1);
      acc[0][0] = MFMA16(a0, wf0, acc[0][0]);
      acc[1][0] = MFMA16(a0, wf1, acc[1][0]);
      acc[2][0] = MFMA16(a0, wf2, acc[2][0]);
      acc[0][1] = MFMA16(a1, wf0, acc[0][1]);
      acc[1][1] = MFMA16(a1, wf1, acc[1][1]);
      acc[2][1] = MFMA16(a1, wf2, acc[2][1]);
      acc[0][2] = MFMA16(a2, wf0, acc[0][2]);
      acc[1][2] = MFMA16(a2, wf1, acc[1][2]);
      acc[2][2] = MFMA16(a2, wf2, acc[2][2]);
      acc[0][3] = MFMA16(a3, wf0, acc[0][3]);
      acc[1][3] = MFMA16(a3, wf1, acc[1][3]);
      acc[2][3] = MFMA16(a3, wf2, acc[2][3]);
      __builtin_amdgcn_s_setprio(0);
      if (ks < 7) { wf0 = nx0; wf1 = nx1; wf2 = nx2; }
    }
    const float bq = qkv_b[h * 64 + wv * 16 + c] * 0.125f;   // SCALE folded into Q path
    const float bk = qkv_b[256 + h * 64 + wv * 16 + c];
    const float bv = qkv_b[512 + h * 64 + wv * 16 + c];
    const int d = wv * 16 + c;
    #pragma unroll
    for (int mi = 0; mi < 4; ++mi) {
      const int row0 = mi * 16 + g * 4;
      unsigned q01 = cvtpk(acc[0][mi][0] + bq, acc[0][mi][1] + bq);
      unsigned q23 = cvtpk(acc[0][mi][2] + bq, acc[0][mi][3] + bq);
      lds[QPS + tsw(row0 + 0, d)] = (unsigned short)q01;
      lds[QPS + tsw(row0 + 1, d)] = (unsigned short)(q01 >> 16);
      lds[QPS + tsw(row0 + 2, d)] = (unsigned short)q23;
      lds[QPS + tsw(row0 + 3, d)] = (unsigned short)(q23 >> 16);
      unsigned k01 = cvtpk(acc[1][mi][0] + bk, acc[1][mi][1] + bk);
      unsigned k23 = cvtpk(acc[1][mi][2] + bk, acc[1][mi][3] + bk);
      lds[KS + tsw(row0 + 0, d)] = (unsigned short)k01;
      lds[KS + tsw(row0 + 1, d)] = (unsigned short)(k01 >> 16);
      lds[KS + tsw(row0 + 2, d)] = (unsigned short)k23;
      lds[KS + tsw(row0 + 3, d)] = (unsigned short)(k23 >> 16);
      unsigned v01 = cvtpk(acc[2][mi][0] + bv, acc[2][mi][1] + bv);
      unsigned v23 = cvtpk(acc[2][mi][2] + bv, acc[2][mi][3] + bv);
      *(uint2*)&lds[VT + tsw(d, row0)] = make_uint2(v01, v23);   // V transposed, b64
    }
    BAR();

    // ---- B2: S = Q K^T for this wave's 16 query rows ----
    f32x4 sacc[4];
    #pragma unroll
    for (int ni = 0; ni < 4; ++ni) sacc[ni] = zero4;
    #pragma unroll
    for (int kk = 0; kk < 2; ++kk) {
      short8 af = *(const short8*)&lds[QPS + tsw(wv * 16 + c, kk * 32 + g * 8)];
      short8 b0 = *(const short8*)&lds[KS + tsw(0 * 16 + c, kk * 32 + g * 8)];
      short8 b1 = *(const short8*)&lds[KS + tsw(1 * 16 + c, kk * 32 + g * 8)];
      short8 b2 = *(const short8*)&lds[KS + tsw(2 * 16 + c, kk * 32 + g * 8)];
      short8 b3 = *(const short8*)&lds[KS + tsw(3 * 16 + c, kk * 32 + g * 8)];
      __builtin_amdgcn_s_setprio(1);
      sacc[0] = MFMA16(af, b0, sacc[0]);
      sacc[1] = MFMA16(af, b1, sacc[1]);
      sacc[2] = MFMA16(af, b2, sacc[2]);
      sacc[3] = MFMA16(af, b3, sacc[3]);
      __builtin_amdgcn_s_setprio(0);
    }

    // ---- B3: +bias+mask, row softmax (DPP rotate-reduce over 16 lanes) ----
    float sv[4][4];
    #pragma unroll
    for (int ni = 0; ni < 4; ++ni)
      #pragma unroll
      for (int r = 0; r < 4; ++r)
        sv[ni][r] = sacc[ni][r] + cbv[ni][r];

    #pragma unroll
    for (int r = 0; r < 4; ++r) {
      float m = fmaxf(fmaxf(sv[0][r], sv[1][r]), fmaxf(sv[2][r], sv[3][r]));
      m = fmaxf(m, dpp_ror<0x128>(m));
      m = fmaxf(m, dpp_ror<0x124>(m));
      m = fmaxf(m, dpp_ror<0x122>(m));
      m = fmaxf(m, dpp_ror<0x121>(m));
      float p[4], s;
      p[0] = __expf(sv[0][r] - m); p[1] = __expf(sv[1][r] - m);
      p[2] = __expf(sv[2][r] - m); p[3] = __expf(sv[3][r] - m);
      s = (p[0] + p[1]) + (p[2] + p[3]);
      s += dpp_ror<0x128>(s);
      s += dpp_ror<0x124>(s);
      s += dpp_ror<0x122>(s);
      s += dpp_ror<0x121>(s);
      const float inv = 1.0f / s;
      const int row = wv * 16 + g * 4 + r;
      unsigned p01 = cvtpk(p[0] * inv, p[1] * inv);
      unsigned p23 = cvtpk(p[2] * inv, p[3] * inv);
      lds[QPS + tsw(row,  0 + c)] = (unsigned short)p01;
      lds[QPS + tsw(row, 16 + c)] = (unsigned short)(p01 >> 16);
      lds[QPS + tsw(row, 32 + c)] = (unsigned short)p23;
      lds[QPS + tsw(row, 48 + c)] = (unsigned short)(p23 >> 16);
    }
    asm volatile("s_waitcnt lgkmcnt(0)" ::: "memory");   // P visible to own-wave reads

    // ---- B4: O_h = P V (accumulate per-head in regs) ----
    #pragma unroll
    for (int kk = 0; kk < 2; ++kk) {
      short8 af = *(const short8*)&lds[QPS + tsw(wv * 16 + c, kk * 32 + g * 8)];
      short8 b0 = *(const short8*)&lds[VT + tsw(0 * 16 + c, kk * 32 + g * 8)];
      short8 b1 = *(const short8*)&lds[VT + tsw(1 * 16 + c, kk * 32 + g * 8)];
      short8 b2 = *(const short8*)&lds[VT + tsw(2 * 16 + c, kk * 32 + g * 8)];
      short8 b3 = *(const short8*)&lds[VT + tsw(3 * 16 + c, kk * 32 + g * 8)];
      __builtin_amdgcn_s_setprio(1);
      oacc[h][0] = MFMA16(af, b0, oacc[h][0]);
      oacc[h][1] = MFMA16(af, b1, oacc[h][1]);
      oacc[h][2] = MFMA16(af, b2, oacc[h][2]);
      oacc[h][3] = MFMA16(af, b3, oacc[h][3]);
      __builtin_amdgcn_s_setprio(0);
    }
    BAR();   // protect QPS/KS/VT/XS before next head / phase C
  }

  // ---- Phase D weight prefetch (ks=0), issued during phase C ----
  const unsigned short* wpb = wp + ((size_t)(wv * 64 + c)) * 256 + g * 8;
  short8 pf0 = *(const short8*)(wpb);
  short8 pf1 = *(const short8*)(wpb + 16 * 256);
  short8 pf2 = *(const short8*)(wpb + 32 * 256);
  short8 pf3 = *(const short8*)(wpb + 48 * 256);

  // ---- Phase C: write O bf16 into XS (rows 0-47) + XR (row 48) ----
  if (wv < 3) {
    #pragma unroll
    for (int h = 0; h < 4; ++h)
      #pragma unroll
      for (int nd = 0; nd < 4; ++nd) {
        const int colc = h * 64 + nd * 16 + c, row0 = wv * 16 + g * 4;
        unsigned o01 = cvtpk(oacc[h][nd][0], oacc[h][nd][1]);
        unsigned o23 = cvtpk(oacc[h][nd][2], oacc[h][nd][3]);
        lds[XS + xsw(row0 + 0, colc)] = (unsigned short)o01;
        lds[XS + xsw(row0 + 1, colc)] = (unsigned short)(o01 >> 16);
        lds[XS + xsw(row0 + 2, colc)] = (unsigned short)o23;
        lds[XS + xsw(row0 + 3, colc)] = (unsigned short)(o23 >> 16);
      }
  } else if (g == 0) {   // wave 3 holds rows 48-63; only row 48 (g==0,r==0) is real
    #pragma unroll
    for (int h = 0; h < 4; ++h)
      #pragma unroll
      for (int nd = 0; nd < 4; ++nd)
        lds[XR + h * 64 + nd * 16 + c] =
            (unsigned short)cvtpk(oacc[h][nd][0], oacc[h][nd][0]);
  }
  BAR();

  // ---- Phase D: out = O @ proj_w + proj_b (k-outer; wave -> 64 cols) ----
  f32x4 pacc[4][4];   // [nj][mi]
  #pragma unroll
  for (int nj = 0; nj < 4; ++nj)
    #pragma unroll
    for (int mi = 0; mi < 4; ++mi) pacc[nj][mi] = zero4;

  short8 wfj0 = pf0, wfj1 = pf1, wfj2 = pf2, wfj3 = pf3;
  #pragma unroll
  for (int ks = 0; ks < 8; ++ks) {
    short8 n0, n1, n2, n3;
    if (ks < 7) {
      n0 = *(const short8*)(wpb + (ks + 1) * 32);
      n1 = *(const short8*)(wpb + 16 * 256 + (ks + 1) * 32);
      n2 = *(const short8*)(wpb + 32 * 256 + (ks + 1) * 32);
      n3 = *(const short8*)(wpb + 48 * 256 + (ks + 1) * 32);
    }
    short8 a0 = *(const short8*)&lds[XS + xsw(0 * 16 + c, ks * 32 + g * 8)];
    short8 a1 = *(const short8*)&lds[XS + xsw(1 * 16 + c, ks * 32 + g * 8)];
    short8 a2 = *(const short8*)&lds[XS + xsw(2 * 16 + c, ks * 32 + g * 8)];
    short8 a3 = *(const short8*)&lds[XR + ks * 32 + g * 8];
    __builtin_amdgcn_s_setprio(1);
    pacc[0][0] = MFMA16(a0, wfj0, pacc[0][0]);
    pacc[1][0] = MFMA16(a0, wfj1, pacc[1][0]);
    pacc[2][0] = MFMA16(a0, wfj2, pacc[2][0]);
    pacc[3][0] = MFMA16(a0, wfj3, pacc[3][0]);
    pacc[0][1] = MFMA16(a1, wfj0, pacc[0][1]);
    pacc[1][1] = MFMA16(a1, wfj1, pacc[1][1]);
    pacc[2][1] = MFMA16(a1, wfj2, pacc[2][1]);
    pacc[3][1] = MFMA16(a1, wfj3, pacc[3][1]);
    pacc[0][2] = MFMA16(a2, wfj0, pacc[0][2]);
    pacc[1][2] = MFMA16(a2, wfj1, pacc[1][2]);
    pacc[2][2] = MFMA16(a2, wfj2, pacc[2][2]);
    pacc[3][2] = MFMA16(a2, wfj3, pacc[3][2]);
    pacc[0][3] = MFMA16(a3, wfj0, pacc[0][3]);
    pacc[1][3] = MFMA16(a3, wfj1, pacc[1][3]);
    pacc[2][3] = MFMA16(a3, wfj2, pacc[2][3]);
    pacc[3][3] = MFMA16(a3, wfj3, pacc[3][3]);
    __builtin_amdgcn_s_setprio(0);
    if (ks < 7) { wfj0 = n0; wfj1 = n1; wfj2 = n2; wfj3 = n3; }
  }
  #pragma unroll
  for (int nj = 0; nj < 4; ++nj) {
    const float pb = proj_b[wv * 64 + nj * 16 + c];
    #pragma unroll
    for (int mi = 0; mi < 3; ++mi) {
      #pragma unroll
      for (int r = 0; r < 4; ++r) {
        const int row = mi * 16 + g * 4 + r;   // 0..47, always valid
        __builtin_nontemporal_store(pacc[nj][mi][r] + pb,
            &out[((size_t)b * 49 + row) * 256 + wv * 64 + nj * 16 + c]);
      }
    }
    if (g == 0)   // mi=3 tile: only row 48 is real
      __builtin_nontemporal_store(pacc[nj][3][0] + pb,
          &out[((size_t)b * 49 + 48) * 256 + wv * 64 + nj * 16 + c]);
  }
}

extern "C" void kernel_launch(void* const* d_in, const int* in_sizes, int n_in,
                              void* d_out, int out_size, void* d_ws, size_t ws_size,
                              hipStream_t stream) {
  const float* x          = (const float*)d_in[0];
  const float* mask       = (const float*)d_in[1];
  const float* qkv_w      = (const float*)d_in[2];
  const float* qkv_b      = (const float*)d_in[3];
  const float* proj_w     = (const float*)d_in[4];
  const float* proj_b     = (const float*)d_in[5];
  const float* bias_table = (const float*)d_in[6];
  const int*   rel_index  = (const int*)d_in[7];
  float* out = (float*)d_out;

  unsigned short* wq = (unsigned short*)d_ws;            // 768*256 bf16
  unsigned short* wp = wq + 768 * 256;                   // 256*256 bf16
  float* comb = (float*)(wp + 256 * 256);                // 64*4*64*64 f32 (~4 MB)

  prep_wqkv<<<768, 256, 0, stream>>>(qkv_w, wq);
  prep_wproj<<<256, 256, 0, stream>>>(proj_w, wp);
  prep_comb<<<4096, 256, 0, stream>>>(mask, bias_table, rel_index, comb);
  win_attn<<<4096, 256, 0, stream>>>(x, qkv_b, proj_b, wq, wp, comb, out);
}

// Round 8
// 369.092 us; speedup vs baseline: 1.2679x; 1.2679x over previous
//
#include <hip/hip_runtime.h>

typedef __attribute__((ext_vector_type(8))) short short8;
typedef __attribute__((ext_vector_type(4))) float f32x4;

#define MFMA16(a, b, c) __builtin_amdgcn_mfma_f32_16x16x32_bf16((a), (b), (c), 0, 0, 0)

template<int CTRL>
__device__ __forceinline__ float dpp_ror(float x) {
  return __builtin_bit_cast(float,
      __builtin_amdgcn_update_dpp(0, __builtin_bit_cast(int, x), CTRL, 0xF, 0xF, false));
}

__device__ __forceinline__ unsigned short f2b(float f) {
  union { float f; unsigned u; } v; v.f = f;
  return (unsigned short)((v.u + 0x7FFFu + ((v.u >> 16) & 1u)) >> 16);  // RNE
}

// ---------------- prep kernels ----------------
// wqkvT[wcol][k] = bf16(qkv_w[k][wcol]) with SCALE folded into Q columns (wcol<256)
__global__ void prep_wqkv(const float* __restrict__ qkv_w, unsigned short* __restrict__ wq) {
  int idx = blockIdx.x * 256 + threadIdx.x;   // 768*256
  int wcol = idx >> 8, k = idx & 255;
  float v = qkv_w[k * 768 + wcol];
  if (wcol < 256) v *= 0.125f;
  wq[idx] = f2b(v);
}

__global__ void prep_wproj(const float* __restrict__ proj_w, unsigned short* __restrict__ wp) {
  int idx = blockIdx.x * 256 + threadIdx.x;   // 256*256
  int col = idx >> 8, k = idx & 255;
  wp[idx] = f2b(proj_w[k * 256 + col]);
}

// comb3[w][h][j=key][i=query] f32: loads as f32x4 straight into the S accumulator.
// valid: mask+bias; key>=49: -1e30 (exp->0); query>=49 (key<49): 0 (rows discarded).
__global__ void prep_comb3(const float* __restrict__ mask, const float* __restrict__ bias_table,
                           const int* __restrict__ rel_index, float* __restrict__ comb3) {
  int idx = blockIdx.x * 256 + threadIdx.x;   // 64*4*64*64 = 1048576
  int i = idx & 63, j = (idx >> 6) & 63, h = (idx >> 12) & 3, w = idx >> 14;
  float v;
  if (j >= 49) v = -1e30f;
  else if (i >= 49) v = 0.f;
  else v = mask[(w * 49 + i) * 49 + j] + bias_table[rel_index[i * 49 + j] * 4 + h];
  comb3[idx] = v;
}

// ---------------- fused window-attention kernel (R1 structure, 383us base) ----------------
// LDS layout (ushort units). Padded row strides (stride%32 dwords == 4 -> 2-way only).
#define XS   0        // [64][264]  x staged as bf16; later aliased by attention output O
#define XLD  264
#define QS   16896    // [64][72]   Q (rows=token, cols=dim, scaled)
#define KS   21504    // [64][72]   K
#define VT   26112    // [64][72]   V transposed: [dim][token]
#define PS   30720    // [64][72]   P (softmax probs), per-wave row slices
#define SLD  72
#define LDS_TOT 35328 // ushorts = 70656 B -> 2 blocks/CU

__global__ __launch_bounds__(256, 2) void win_attn(
    const float* __restrict__ x, const float* __restrict__ qkv_b,
    const float* __restrict__ proj_b, const unsigned short* __restrict__ wq,
    const unsigned short* __restrict__ wp, const float* __restrict__ comb3,
    float* __restrict__ out)
{
  __shared__ alignas(16) unsigned short lds[LDS_TOT];
  const int b = blockIdx.x, tid = threadIdx.x;
  const int wv = tid >> 6, l = tid & 63, g = l >> 4, c = l & 15;

  // ---- Phase A: stage x[b] -> bf16 LDS, rows >= 49 zeroed ----
  {
    const float4* xb = (const float4*)(x + (size_t)b * (49 * 256));
    #pragma unroll
    for (int it = 0; it < 16; ++it) {
      int idx = tid + it * 256, row = idx >> 6, c4 = idx & 63;
      float4 v = make_float4(0.f, 0.f, 0.f, 0.f);
      if (row < 49) v = xb[row * 64 + c4];
      ushort4 pk = make_ushort4(f2b(v.x), f2b(v.y), f2b(v.z), f2b(v.w));
      *(ushort4*)&lds[XS + row * XLD + c4 * 4] = pk;
    }
  }
  __syncthreads();

  f32x4 zero4 = {0.f, 0.f, 0.f, 0.f};
  f32x4 oacc[4][4];
  #pragma unroll
  for (int h = 0; h < 4; ++h)
    #pragma unroll
    for (int nd = 0; nd < 4; ++nd) oacc[h][nd] = zero4;

  #pragma unroll
  for (int h = 0; h < 4; ++h) {
    // ---- B1: QKV GEMM for head h; this wave computes a 16-col slice of Q,K,V ----
    #pragma unroll
    for (int dst = 0; dst < 3; ++dst) {
      const int wcol0 = dst * 256 + h * 64 + wv * 16;
      f32x4 acc[4];
      #pragma unroll
      for (int mi = 0; mi < 4; ++mi) acc[mi] = zero4;
      #pragma unroll
      for (int ks = 0; ks < 8; ++ks) {
        const int k0 = ks * 32 + g * 8;
        short8 bf = *(const short8*)(wq + (size_t)(wcol0 + c) * 256 + k0);
        #pragma unroll
        for (int mi = 0; mi < 4; ++mi) {
          short8 af = *(const short8*)&lds[XS + (mi * 16 + c) * XLD + k0];
          acc[mi] = MFMA16(af, bf, acc[mi]);
        }
      }
      float bias = qkv_b[wcol0 + c];
      if (dst == 0) bias *= 0.125f;   // SCALE folded into Q path (weights pre-scaled too)
      const int d = wv * 16 + c;   // within-head dim of this slice
      #pragma unroll
      for (int mi = 0; mi < 4; ++mi) {
        #pragma unroll
        for (int r = 0; r < 4; ++r) {
          const int row = mi * 16 + g * 4 + r;   // token
          const unsigned short bv = f2b(acc[mi][r] + bias);
          if (dst == 0)      lds[QS + row * SLD + d] = bv;
          else if (dst == 1) lds[KS + row * SLD + d] = bv;
          else               lds[VT + d * SLD + row] = bv;   // V transposed
        }
      }
    }
    __syncthreads();

    // ---- B2: S = comb3 + Q K^T (comb3 loads directly into the MFMA accumulator) ----
    const float* cb3 = comb3 + (((size_t)(b & 63)) * 4 + h) * 4096;
    f32x4 sacc[4];
    #pragma unroll
    for (int ni = 0; ni < 4; ++ni)
      sacc[ni] = *(const f32x4*)(cb3 + (ni * 16 + c) * 64 + wv * 16 + g * 4);
    #pragma unroll
    for (int kk = 0; kk < 2; ++kk) {
      short8 af = *(const short8*)&lds[QS + (wv * 16 + c) * SLD + kk * 32 + g * 8];
      #pragma unroll
      for (int ni = 0; ni < 4; ++ni) {
        short8 bf = *(const short8*)&lds[KS + (ni * 16 + c) * SLD + kk * 32 + g * 8];
        sacc[ni] = MFMA16(af, bf, sacc[ni]);
      }
    }

    // ---- B3: row softmax (16-lane DPP rotate-reduce), P -> LDS ----
    #pragma unroll
    for (int r = 0; r < 4; ++r) {
      float m = fmaxf(fmaxf(sacc[0][r], sacc[1][r]), fmaxf(sacc[2][r], sacc[3][r]));
      m = fmaxf(m, dpp_ror<0x128>(m));
      m = fmaxf(m, dpp_ror<0x124>(m));
      m = fmaxf(m, dpp_ror<0x122>(m));
      m = fmaxf(m, dpp_ror<0x121>(m));
      float p[4], s;
      p[0] = __expf(sacc[0][r] - m); p[1] = __expf(sacc[1][r] - m);
      p[2] = __expf(sacc[2][r] - m); p[3] = __expf(sacc[3][r] - m);
      s = (p[0] + p[1]) + (p[2] + p[3]);
      s += dpp_ror<0x128>(s);
      s += dpp_ror<0x124>(s);
      s += dpp_ror<0x122>(s);
      s += dpp_ror<0x121>(s);
      const float inv = 1.0f / s;
      const int row = wv * 16 + g * 4 + r;
      #pragma unroll
      for (int ni = 0; ni < 4; ++ni)
        lds[PS + row * SLD + ni * 16 + c] = f2b(p[ni] * inv);
    }

    // ---- B4: O_h = P V (accumulate per-head in regs) ----
    #pragma unroll
    for (int kk = 0; kk < 2; ++kk) {
      short8 af = *(const short8*)&lds[PS + (wv * 16 + c) * SLD + kk * 32 + g * 8];
      #pragma unroll
      for (int nd = 0; nd < 4; ++nd) {
        short8 bf = *(const short8*)&lds[VT + (nd * 16 + c) * SLD + kk * 32 + g * 8];
        oacc[h][nd] = MFMA16(af, bf, oacc[h][nd]);
      }
    }
    __syncthreads();   // protect QS/KS/VT before next head overwrites
  }

  // ---- Phase C: write O bf16 into XS region (x is dead now) ----
  #pragma unroll
  for (int h = 0; h < 4; ++h)
    #pragma unroll
    for (int nd = 0; nd < 4; ++nd)
      #pragma unroll
      for (int r = 0; r < 4; ++r)
        lds[XS + (wv * 16 + g * 4 + r) * XLD + h * 64 + nd * 16 + c] = f2b(oacc[h][nd][r]);
  __syncthreads();

  // ---- Phase D: out = O @ proj_w + proj_b (this wave: 64 output cols) ----
  #pragma unroll
  for (int nj = 0; nj < 4; ++nj) {
    const int col0 = wv * 64 + nj * 16;
    f32x4 pacc[4];
    #pragma unroll
    for (int mi = 0; mi < 4; ++mi) pacc[mi] = zero4;
    #pragma unroll
    for (int ks = 0; ks < 8; ++ks) {
      const int k0 = ks * 32 + g * 8;
      short8 bf = *(const short8*)(wp + (size_t)(col0 + c) * 256 + k0);
      #pragma unroll
      for (int mi = 0; mi < 4; ++mi) {
        short8 af = *(const short8*)&lds[XS + (mi * 16 + c) * XLD + k0];
        pacc[mi] = MFMA16(af, bf, pacc[mi]);
      }
    }
    const float pb = proj_b[col0 + c];
    #pragma unroll
    for (int mi = 0; mi < 4; ++mi) {
      #pragma unroll
      for (int r = 0; r < 4; ++r) {
        const int row = mi * 16 + g * 4 + r;
        if (row < 49)
          out[((size_t)b * 49 + row) * 256 + col0 + c] = pacc[mi][r] + pb;
      }
    }
  }
}

extern "C" void kernel_launch(void* const* d_in, const int* in_sizes, int n_in,
                              void* d_out, int out_size, void* d_ws, size_t ws_size,
                              hipStream_t stream) {
  const float* x          = (const float*)d_in[0];
  const float* mask       = (const float*)d_in[1];
  const float* qkv_w      = (const float*)d_in[2];
  const float* qkv_b      = (const float*)d_in[3];
  const float* proj_w     = (const float*)d_in[4];
  const float* proj_b     = (const float*)d_in[5];
  const float* bias_table = (const float*)d_in[6];
  const int*   rel_index  = (const int*)d_in[7];
  float* out = (float*)d_out;

  unsigned short* wq = (unsigned short*)d_ws;            // 768*256 bf16
  unsigned short* wp = wq + 768 * 256;                   // 256*256 bf16
  float* comb3 = (float*)(wp + 256 * 256);               // 64*4*64*64 f32 (~4 MB)

  prep_wqkv<<<768, 256, 0, stream>>>(qkv_w, wq);
  prep_wproj<<<256, 256, 0, stream>>>(proj_w, wp);
  prep_comb3<<<4096, 256, 0, stream>>>(mask, bias_table, rel_index, comb3);
  win_attn<<<4096, 256, 0, stream>>>(x, qkv_b, proj_b, wq, wp, comb3, out);
}

// Round 9
// 357.598 us; speedup vs baseline: 1.3086x; 1.0321x over previous
//
#include <hip/hip_runtime.h>

typedef __attribute__((ext_vector_type(8))) short short8;
typedef __attribute__((ext_vector_type(4))) float f32x4;

#define MFMA16(a, b, c) __builtin_amdgcn_mfma_f32_16x16x32_bf16((a), (b), (c), 0, 0, 0)

// raw barrier: LDS visibility only (lgkmcnt), leaves global prefetches (vmcnt) in flight
#define BAR() do { asm volatile("s_waitcnt lgkmcnt(0)" ::: "memory"); \
                   __builtin_amdgcn_s_barrier(); \
                   asm volatile("" ::: "memory"); } while (0)

template<int CTRL>
__device__ __forceinline__ float dpp_ror(float x) {
  return __builtin_bit_cast(float,
      __builtin_amdgcn_update_dpp(0, __builtin_bit_cast(int, x), CTRL, 0xF, 0xF, false));
}

__device__ __forceinline__ unsigned cvtpk(float lo, float hi) {
  unsigned r;
  asm("v_cvt_pk_bf16_f32 %0, %1, %2" : "=v"(r) : "v"(lo), "v"(hi));
  return r;
}

__device__ __forceinline__ unsigned short f2b(float f) {
  union { float f; unsigned u; } v; v.f = f;
  return (unsigned short)((v.u + 0x7FFFu + ((v.u >> 16) & 1u)) >> 16);  // RNE
}

// ---------------- prep kernels ----------------
// wqkvT[wcol][k] = bf16(qkv_w[k][wcol]) with SCALE folded into Q columns (wcol<256)
__global__ void prep_wqkv(const float* __restrict__ qkv_w, unsigned short* __restrict__ wq) {
  int idx = blockIdx.x * 256 + threadIdx.x;   // 768*256
  int wcol = idx >> 8, k = idx & 255;
  float v = qkv_w[k * 768 + wcol];
  if (wcol < 256) v *= 0.125f;
  wq[idx] = f2b(v);
}

__global__ void prep_wproj(const float* __restrict__ proj_w, unsigned short* __restrict__ wp) {
  int idx = blockIdx.x * 256 + threadIdx.x;   // 256*256
  int col = idx >> 8, k = idx & 255;
  wp[idx] = f2b(proj_w[k * 256 + col]);
}

// comb3[w][h][j=key][i=query] f32: loads as f32x4 straight into the S accumulator.
__global__ void prep_comb3(const float* __restrict__ mask, const float* __restrict__ bias_table,
                           const int* __restrict__ rel_index, float* __restrict__ comb3) {
  int idx = blockIdx.x * 256 + threadIdx.x;   // 64*4*64*64 = 1048576
  int i = idx & 63, j = (idx >> 6) & 63, h = (idx >> 12) & 3, w = idx >> 14;
  float v;
  if (j >= 49) v = -1e30f;
  else if (i >= 49) v = 0.f;
  else v = mask[(w * 49 + i) * 49 + j] + bias_table[rel_index[i * 49 + j] * 4 + h];
  comb3[idx] = v;
}

// ---------------- fused window-attention kernel ----------------
// LDS layout (ushort units). Padded row strides (stride%32 dwords == 4 -> 2-way only).
#define XS   0        // [64][264]  x staged as bf16; later aliased by attention output O
#define XLD  264
#define QS   16896    // [64][72]   Q (rows=token, cols=dim, scaled)
#define KS   21504    // [64][72]   K
#define VT   26112    // [64][72]   V transposed: [dim][token]
#define PS   30720    // [64][72]   P (softmax probs), per-wave row slices
#define SLD  72
#define LDS_TOT 35328 // ushorts = 70656 B -> 2 blocks/CU

__global__ __launch_bounds__(256, 2) void win_attn(
    const float* __restrict__ x, const float* __restrict__ qkv_b,
    const float* __restrict__ proj_b, const unsigned short* __restrict__ wq,
    const unsigned short* __restrict__ wp, const float* __restrict__ comb3,
    float* __restrict__ out)
{
  __shared__ alignas(16) unsigned short lds[LDS_TOT];
  const int b = blockIdx.x, tid = threadIdx.x;
  const int wv = tid >> 6, l = tid & 63, g = l >> 4, c = l & 15;

  // ---- Phase A: stage x[b] -> bf16 LDS, rows >= 49 zeroed ----
  {
    const float4* xb = (const float4*)(x + (size_t)b * (49 * 256));
    #pragma unroll
    for (int it = 0; it < 16; ++it) {
      int idx = tid + it * 256, row = idx >> 6, c4 = idx & 63;
      float4 v = make_float4(0.f, 0.f, 0.f, 0.f);
      if (row < 49) v = xb[row * 64 + c4];
      ushort4 pk = make_ushort4(f2b(v.x), f2b(v.y), f2b(v.z), f2b(v.w));
      *(ushort4*)&lds[XS + row * XLD + c4 * 4] = pk;
    }
  }
  BAR();

  f32x4 zero4 = {0.f, 0.f, 0.f, 0.f};
  f32x4 oacc[4][4];
  #pragma unroll
  for (int h = 0; h < 4; ++h)
    #pragma unroll
    for (int nd = 0; nd < 4; ++nd) oacc[h][nd] = zero4;

  #pragma unroll
  for (int h = 0; h < 4; ++h) {
    // ---- comb3 prefetch: loads issued ~B1-duration ahead of use in B2,
    //      directly into the S accumulator (S born with bias+mask) ----
    const float* cb3 = comb3 + (((size_t)(b & 63)) * 4 + h) * 4096;
    f32x4 sacc[4];
    #pragma unroll
    for (int ni = 0; ni < 4; ++ni)
      sacc[ni] = *(const f32x4*)(cb3 + (ni * 16 + c) * 64 + wv * 16 + g * 4);

    // ---- B1: QKV GEMM for head h, merged-dst: one X A-frag feeds Q,K,V MFMAs ----
    f32x4 acc[3][4];
    #pragma unroll
    for (int dst = 0; dst < 3; ++dst)
      #pragma unroll
      for (int mi = 0; mi < 4; ++mi) acc[dst][mi] = zero4;

    const unsigned short* wbase = wq + ((size_t)(h * 64 + wv * 16 + c)) * 256 + g * 8;
    #pragma unroll
    for (int ks = 0; ks < 8; ++ks) {
      const int k0 = ks * 32;
      short8 bf0 = *(const short8*)(wbase + k0);            // Q weights
      short8 bf1 = *(const short8*)(wbase + 65536 + k0);    // K weights
      short8 bf2 = *(const short8*)(wbase + 131072 + k0);   // V weights
      #pragma unroll
      for (int mi = 0; mi < 4; ++mi) {
        short8 af = *(const short8*)&lds[XS + (mi * 16 + c) * XLD + k0 + g * 8];
        acc[0][mi] = MFMA16(af, bf0, acc[0][mi]);
        acc[1][mi] = MFMA16(af, bf1, acc[1][mi]);
        acc[2][mi] = MFMA16(af, bf2, acc[2][mi]);
      }
    }
    const float bq = qkv_b[h * 64 + wv * 16 + c] * 0.125f;   // SCALE folded into Q path
    const float bk = qkv_b[256 + h * 64 + wv * 16 + c];
    const float bv = qkv_b[512 + h * 64 + wv * 16 + c];
    const int d = wv * 16 + c;
    #pragma unroll
    for (int mi = 0; mi < 4; ++mi) {
      const int row0 = mi * 16 + g * 4;
      #pragma unroll
      for (int r = 0; r < 4; ++r) {
        lds[QS + (row0 + r) * SLD + d] = f2b(acc[0][mi][r] + bq);
        lds[KS + (row0 + r) * SLD + d] = f2b(acc[1][mi][r] + bk);
      }
      ushort4 vp;
      vp.x = f2b(acc[2][mi][0] + bv); vp.y = f2b(acc[2][mi][1] + bv);
      vp.z = f2b(acc[2][mi][2] + bv); vp.w = f2b(acc[2][mi][3] + bv);
      *(ushort4*)&lds[VT + d * SLD + row0] = vp;   // V transposed, packed b64
    }
    BAR();

    // ---- B2: S = comb3 + Q K^T (accumulator pre-loaded) ----
    #pragma unroll
    for (int kk = 0; kk < 2; ++kk) {
      short8 af = *(const short8*)&lds[QS + (wv * 16 + c) * SLD + kk * 32 + g * 8];
      #pragma unroll
      for (int ni = 0; ni < 4; ++ni) {
        short8 bf = *(const short8*)&lds[KS + (ni * 16 + c) * SLD + kk * 32 + g * 8];
        sacc[ni] = MFMA16(af, bf, sacc[ni]);
      }
    }

    // ---- B3: row softmax (16-lane DPP rotate-reduce), P -> LDS ----
    #pragma unroll
    for (int r = 0; r < 4; ++r) {
      float m = fmaxf(fmaxf(sacc[0][r], sacc[1][r]), fmaxf(sacc[2][r], sacc[3][r]));
      m = fmaxf(m, dpp_ror<0x128>(m));
      m = fmaxf(m, dpp_ror<0x124>(m));
      m = fmaxf(m, dpp_ror<0x122>(m));
      m = fmaxf(m, dpp_ror<0x121>(m));
      float p[4], s;
      p[0] = __expf(sacc[0][r] - m); p[1] = __expf(sacc[1][r] - m);
      p[2] = __expf(sacc[2][r] - m); p[3] = __expf(sacc[3][r] - m);
      s = (p[0] + p[1]) + (p[2] + p[3]);
      s += dpp_ror<0x128>(s);
      s += dpp_ror<0x124>(s);
      s += dpp_ror<0x122>(s);
      s += dpp_ror<0x121>(s);
      const float inv = 1.0f / s;
      const int row = wv * 16 + g * 4 + r;
      #pragma unroll
      for (int ni = 0; ni < 4; ++ni)
        lds[PS + row * SLD + ni * 16 + c] = f2b(p[ni] * inv);
    }

    // ---- B4: O_h = P V (accumulate per-head in regs) ----
    #pragma unroll
    for (int kk = 0; kk < 2; ++kk) {
      short8 af = *(const short8*)&lds[PS + (wv * 16 + c) * SLD + kk * 32 + g * 8];
      #pragma unroll
      for (int nd = 0; nd < 4; ++nd) {
        short8 bf = *(const short8*)&lds[VT + (nd * 16 + c) * SLD + kk * 32 + g * 8];
        oacc[h][nd] = MFMA16(af, bf, oacc[h][nd]);
      }
    }
    BAR();   // protect QS/KS/VT before next head overwrites
  }

  // ---- Phase D weight prefetch (ks=0), issued before the phase-C LDS writes ----
  const unsigned short* wpb = wp + ((size_t)(wv * 64 + c)) * 256 + g * 8;
  short8 pf0 = *(const short8*)(wpb);
  short8 pf1 = *(const short8*)(wpb + 4096);
  short8 pf2 = *(const short8*)(wpb + 8192);
  short8 pf3 = *(const short8*)(wpb + 12288);

  // ---- Phase C: write O bf16 into XS region (x is dead now) ----
  #pragma unroll
  for (int h = 0; h < 4; ++h)
    #pragma unroll
    for (int nd = 0; nd < 4; ++nd)
      #pragma unroll
      for (int r = 0; r < 4; ++r)
        lds[XS + (wv * 16 + g * 4 + r) * XLD + h * 64 + nd * 16 + c] = f2b(oacc[h][nd][r]);
  BAR();

  // ---- Phase D: out = O @ proj_w + proj_b, k-outer (A-frag feeds 4 col-tiles) ----
  f32x4 pacc[4][4];   // [nj][mi]
  #pragma unroll
  for (int nj = 0; nj < 4; ++nj)
    #pragma unroll
    for (int mi = 0; mi < 4; ++mi) pacc[nj][mi] = zero4;

  short8 wf0 = pf0, wf1 = pf1, wf2 = pf2, wf3 = pf3;
  #pragma unroll
  for (int ks = 0; ks < 8; ++ks) {
    short8 n0, n1, n2, n3;
    if (ks < 7) {
      n0 = *(const short8*)(wpb + (ks + 1) * 32);
      n1 = *(const short8*)(wpb + 4096 + (ks + 1) * 32);
      n2 = *(const short8*)(wpb + 8192 + (ks + 1) * 32);
      n3 = *(const short8*)(wpb + 12288 + (ks + 1) * 32);
    }
    #pragma unroll
    for (int mi = 0; mi < 4; ++mi) {
      short8 af = *(const short8*)&lds[XS + (mi * 16 + c) * XLD + ks * 32 + g * 8];
      pacc[0][mi] = MFMA16(af, wf0, pacc[0][mi]);
      pacc[1][mi] = MFMA16(af, wf1, pacc[1][mi]);
      pacc[2][mi] = MFMA16(af, wf2, pacc[2][mi]);
      pacc[3][mi] = MFMA16(af, wf3, pacc[3][mi]);
    }
    if (ks < 7) { wf0 = n0; wf1 = n1; wf2 = n2; wf3 = n3; }
  }
  #pragma unroll
  for (int nj = 0; nj < 4; ++nj) {
    const float pb = proj_b[wv * 64 + nj * 16 + c];
    #pragma unroll
    for (int mi = 0; mi < 4; ++mi) {
      #pragma unroll
      for (int r = 0; r < 4; ++r) {
        const int row = mi * 16 + g * 4 + r;
        if (row < 49)
          out[((size_t)b * 49 + row) * 256 + wv * 64 + nj * 16 + c] = pacc[nj][mi][r] + pb;
      }
    }
  }
}

extern "C" void kernel_launch(void* const* d_in, const int* in_sizes, int n_in,
                              void* d_out, int out_size, void* d_ws, size_t ws_size,
                              hipStream_t stream) {
  const float* x          = (const float*)d_in[0];
  const float* mask       = (const float*)d_in[1];
  const float* qkv_w      = (const float*)d_in[2];
  const float* qkv_b      = (const float*)d_in[3];
  const float* proj_w     = (const float*)d_in[4];
  const float* proj_b     = (const float*)d_in[5];
  const float* bias_table = (const float*)d_in[6];
  const int*   rel_index  = (const int*)d_in[7];
  float* out = (float*)d_out;

  unsigned short* wq = (unsigned short*)d_ws;            // 768*256 bf16
  unsigned short* wp = wq + 768 * 256;                   // 256*256 bf16
  float* comb3 = (float*)(wp + 256 * 256);               // 64*4*64*64 f32 (~4 MB)

  prep_wqkv<<<768, 256, 0, stream>>>(qkv_w, wq);
  prep_wproj<<<256, 256, 0, stream>>>(proj_w, wp);
  prep_comb3<<<4096, 256, 0, stream>>>(mask, bias_table, rel_index, comb3);
  win_attn<<<4096, 256, 0, stream>>>(x, qkv_b, proj_b, wq, wp, comb3, out);
}

// Round 10
// 346.841 us; speedup vs baseline: 1.3492x; 1.0310x over previous
//
#include <hip/hip_runtime.h>

typedef __attribute__((ext_vector_type(8))) short short8;
typedef __attribute__((ext_vector_type(4))) float f32x4;

#define MFMA16(a, b, c) __builtin_amdgcn_mfma_f32_16x16x32_bf16((a), (b), (c), 0, 0, 0)

// raw barrier: LDS visibility only (lgkmcnt), leaves global prefetches (vmcnt) in flight
#define BAR() do { asm volatile("s_waitcnt lgkmcnt(0)" ::: "memory"); \
                   __builtin_amdgcn_s_barrier(); \
                   asm volatile("" ::: "memory"); } while (0)

template<int CTRL>
__device__ __forceinline__ float dpp_ror(float x) {
  return __builtin_bit_cast(float,
      __builtin_amdgcn_update_dpp(0, __builtin_bit_cast(int, x), CTRL, 0xF, 0xF, false));
}

__device__ __forceinline__ unsigned cvtpk(float lo, float hi) {
  unsigned r;
  asm("v_cvt_pk_bf16_f32 %0, %1, %2" : "=v"(r) : "v"(lo), "v"(hi));
  return r;
}

__device__ __forceinline__ unsigned short f2b(float f) {
  union { float f; unsigned u; } v; v.f = f;
  return (unsigned short)((v.u + 0x7FFFu + ((v.u >> 16) & 1u)) >> 16);  // RNE
}

// ---------------- prep kernels ----------------
// wqkvT[wcol][k] = bf16(qkv_w[k][wcol]) with SCALE folded into Q columns (wcol<256)
__global__ void prep_wqkv(const float* __restrict__ qkv_w, unsigned short* __restrict__ wq) {
  int idx = blockIdx.x * 256 + threadIdx.x;   // 768*256
  int wcol = idx >> 8, k = idx & 255;
  float v = qkv_w[k * 768 + wcol];
  if (wcol < 256) v *= 0.125f;
  wq[idx] = f2b(v);
}

__global__ void prep_wproj(const float* __restrict__ proj_w, unsigned short* __restrict__ wp) {
  int idx = blockIdx.x * 256 + threadIdx.x;   // 256*256
  int col = idx >> 8, k = idx & 255;
  wp[idx] = f2b(proj_w[k * 256 + col]);
}

// comb3[w][h][j=key][i=query] f32: loads as f32x4 straight into the S accumulator.
__global__ void prep_comb3(const float* __restrict__ mask, const float* __restrict__ bias_table,
                           const int* __restrict__ rel_index, float* __restrict__ comb3) {
  int idx = blockIdx.x * 256 + threadIdx.x;   // 64*4*64*64 = 1048576
  int i = idx & 63, j = (idx >> 6) & 63, h = (idx >> 12) & 3, w = idx >> 14;
  float v;
  if (j >= 49) v = -1e30f;
  else if (i >= 49) v = 0.f;
  else v = mask[(w * 49 + i) * 49 + j] + bias_table[rel_index[i * 49 + j] * 4 + h];
  comb3[idx] = v;
}

// ---------------- fused window-attention kernel ----------------
// LDS layout (ushort units). Padded row strides (stride%32 dwords == 4 -> 2-way only).
#define XS   0        // [64][264]  x staged as bf16; later aliased by attention output O
#define XLD  264
#define QS   16896    // [64][72]   Q (rows=token, cols=dim, scaled)
#define KS   21504    // [64][72]   K
#define VT   26112    // [64][72]   V transposed: [dim][token]
#define PS   30720    // [64][72]   P (softmax probs), per-wave row slices
#define SLD  72
#define LDS_TOT 35328 // ushorts = 70656 B -> 2 blocks/CU

__global__ __launch_bounds__(256, 2) void win_attn(
    const float* __restrict__ x, const float* __restrict__ qkv_b,
    const float* __restrict__ proj_b, const unsigned short* __restrict__ wq,
    const unsigned short* __restrict__ wp, const float* __restrict__ comb3,
    float* __restrict__ out)
{
  __shared__ alignas(16) unsigned short lds[LDS_TOT];
  const int b = blockIdx.x, tid = threadIdx.x;
  const int wv = tid >> 6, l = tid & 63, g = l >> 4, c = l & 15;

  // ---- Phase A: stage x[b] -> bf16 LDS (cvtpk packed), rows >= 49 zeroed ----
  {
    const float4* xb = (const float4*)(x + (size_t)b * (49 * 256));
    #pragma unroll
    for (int it = 0; it < 16; ++it) {
      int idx = tid + it * 256, row = idx >> 6, c4 = idx & 63;
      float4 v = make_float4(0.f, 0.f, 0.f, 0.f);
      if (row < 49) v = xb[row * 64 + c4];
      uint2 pk = make_uint2(cvtpk(v.x, v.y), cvtpk(v.z, v.w));
      *(uint2*)&lds[XS + row * XLD + c4 * 4] = pk;
    }
  }
  BAR();

  f32x4 zero4 = {0.f, 0.f, 0.f, 0.f};
  f32x4 oacc[4][4];
  #pragma unroll
  for (int h = 0; h < 4; ++h)
    #pragma unroll
    for (int nd = 0; nd < 4; ++nd) oacc[h][nd] = zero4;

  #pragma unroll
  for (int h = 0; h < 4; ++h) {
    // ---- comb3 prefetch: issued ~B1-duration ahead of B2, straight into S acc ----
    const float* cb3 = comb3 + (((size_t)(b & 63)) * 4 + h) * 4096;
    f32x4 sacc[4];
    #pragma unroll
    for (int ni = 0; ni < 4; ++ni)
      sacc[ni] = *(const f32x4*)(cb3 + (ni * 16 + c) * 64 + wv * 16 + g * 4);

    // ---- B1: QKV GEMM, merged-dst + 1-step weight lookahead ----
    f32x4 acc[3][4];
    #pragma unroll
    for (int dst = 0; dst < 3; ++dst)
      #pragma unroll
      for (int mi = 0; mi < 4; ++mi) acc[dst][mi] = zero4;

    const unsigned short* wbase = wq + ((size_t)(h * 64 + wv * 16 + c)) * 256 + g * 8;
    short8 wf0 = *(const short8*)(wbase);
    short8 wf1 = *(const short8*)(wbase + 65536);
    short8 wf2 = *(const short8*)(wbase + 131072);
    #pragma unroll
    for (int ks = 0; ks < 8; ++ks) {
      short8 nx0, nx1, nx2;
      if (ks < 7) {
        nx0 = *(const short8*)(wbase + (ks + 1) * 32);
        nx1 = *(const short8*)(wbase + 65536 + (ks + 1) * 32);
        nx2 = *(const short8*)(wbase + 131072 + (ks + 1) * 32);
      }
      #pragma unroll
      for (int mi = 0; mi < 4; ++mi) {
        short8 af = *(const short8*)&lds[XS + (mi * 16 + c) * XLD + ks * 32 + g * 8];
        acc[0][mi] = MFMA16(af, wf0, acc[0][mi]);
        acc[1][mi] = MFMA16(af, wf1, acc[1][mi]);
        acc[2][mi] = MFMA16(af, wf2, acc[2][mi]);
      }
      if (ks < 7) { wf0 = nx0; wf1 = nx1; wf2 = nx2; }
    }
    const float bq = qkv_b[h * 64 + wv * 16 + c] * 0.125f;   // SCALE folded into Q path
    const float bk = qkv_b[256 + h * 64 + wv * 16 + c];
    const float bv = qkv_b[512 + h * 64 + wv * 16 + c];
    const int d = wv * 16 + c;
    #pragma unroll
    for (int mi = 0; mi < 4; ++mi) {
      const int row0 = mi * 16 + g * 4;
      unsigned q01 = cvtpk(acc[0][mi][0] + bq, acc[0][mi][1] + bq);
      unsigned q23 = cvtpk(acc[0][mi][2] + bq, acc[0][mi][3] + bq);
      lds[QS + (row0 + 0) * SLD + d] = (unsigned short)q01;
      lds[QS + (row0 + 1) * SLD + d] = (unsigned short)(q01 >> 16);
      lds[QS + (row0 + 2) * SLD + d] = (unsigned short)q23;
      lds[QS + (row0 + 3) * SLD + d] = (unsigned short)(q23 >> 16);
      unsigned k01 = cvtpk(acc[1][mi][0] + bk, acc[1][mi][1] + bk);
      unsigned k23 = cvtpk(acc[1][mi][2] + bk, acc[1][mi][3] + bk);
      lds[KS + (row0 + 0) * SLD + d] = (unsigned short)k01;
      lds[KS + (row0 + 1) * SLD + d] = (unsigned short)(k01 >> 16);
      lds[KS + (row0 + 2) * SLD + d] = (unsigned short)k23;
      lds[KS + (row0 + 3) * SLD + d] = (unsigned short)(k23 >> 16);
      unsigned v01 = cvtpk(acc[2][mi][0] + bv, acc[2][mi][1] + bv);
      unsigned v23 = cvtpk(acc[2][mi][2] + bv, acc[2][mi][3] + bv);
      *(uint2*)&lds[VT + d * SLD + row0] = make_uint2(v01, v23);   // V transposed, b64
    }
    BAR();

    // ---- B2: S = comb3 + Q K^T (accumulator pre-loaded) ----
    #pragma unroll
    for (int kk = 0; kk < 2; ++kk) {
      short8 af = *(const short8*)&lds[QS + (wv * 16 + c) * SLD + kk * 32 + g * 8];
      #pragma unroll
      for (int ni = 0; ni < 4; ++ni) {
        short8 bf = *(const short8*)&lds[KS + (ni * 16 + c) * SLD + kk * 32 + g * 8];
        sacc[ni] = MFMA16(af, bf, sacc[ni]);
      }
    }

    // ---- B3: row softmax (16-lane DPP rotate-reduce), P -> LDS ----
    #pragma unroll
    for (int r = 0; r < 4; ++r) {
      float m = fmaxf(fmaxf(sacc[0][r], sacc[1][r]), fmaxf(sacc[2][r], sacc[3][r]));
      m = fmaxf(m, dpp_ror<0x128>(m));
      m = fmaxf(m, dpp_ror<0x124>(m));
      m = fmaxf(m, dpp_ror<0x122>(m));
      m = fmaxf(m, dpp_ror<0x121>(m));
      float p[4], s;
      p[0] = __expf(sacc[0][r] - m); p[1] = __expf(sacc[1][r] - m);
      p[2] = __expf(sacc[2][r] - m); p[3] = __expf(sacc[3][r] - m);
      s = (p[0] + p[1]) + (p[2] + p[3]);
      s += dpp_ror<0x128>(s);
      s += dpp_ror<0x124>(s);
      s += dpp_ror<0x122>(s);
      s += dpp_ror<0x121>(s);
      const float inv = 1.0f / s;
      const int row = wv * 16 + g * 4 + r;
      #pragma unroll
      for (int ni = 0; ni < 4; ++ni)
        lds[PS + row * SLD + ni * 16 + c] = f2b(p[ni] * inv);
    }

    // ---- B4: O_h = P V (accumulate per-head in regs) ----
    #pragma unroll
    for (int kk = 0; kk < 2; ++kk) {
      short8 af = *(const short8*)&lds[PS + (wv * 16 + c) * SLD + kk * 32 + g * 8];
      #pragma unroll
      for (int nd = 0; nd < 4; ++nd) {
        short8 bf = *(const short8*)&lds[VT + (nd * 16 + c) * SLD + kk * 32 + g * 8];
        oacc[h][nd] = MFMA16(af, bf, oacc[h][nd]);
      }
    }
    BAR();   // protect QS/KS/VT before next head overwrites
  }

  // ---- Phase D weight prefetch (ks=0), issued before the phase-C LDS writes ----
  const unsigned short* wpb = wp + ((size_t)(wv * 64 + c)) * 256 + g * 8;
  short8 pf0 = *(const short8*)(wpb);
  short8 pf1 = *(const short8*)(wpb + 4096);
  short8 pf2 = *(const short8*)(wpb + 8192);
  short8 pf3 = *(const short8*)(wpb + 12288);

  // ---- Phase C: write O bf16 into XS region (x is dead now), cvtpk packed ----
  #pragma unroll
  for (int h = 0; h < 4; ++h)
    #pragma unroll
    for (int nd = 0; nd < 4; ++nd) {
      const int colc = h * 64 + nd * 16 + c, row0 = wv * 16 + g * 4;
      unsigned o01 = cvtpk(oacc[h][nd][0], oacc[h][nd][1]);
      unsigned o23 = cvtpk(oacc[h][nd][2], oacc[h][nd][3]);
      lds[XS + (row0 + 0) * XLD + colc] = (unsigned short)o01;
      lds[XS + (row0 + 1) * XLD + colc] = (unsigned short)(o01 >> 16);
      lds[XS + (row0 + 2) * XLD + colc] = (unsigned short)o23;
      lds[XS + (row0 + 3) * XLD + colc] = (unsigned short)(o23 >> 16);
    }
  BAR();

  // ---- Phase D: out = O @ proj_w + proj_b, k-outer (A-frag feeds 4 col-tiles) ----
  f32x4 pacc[4][4];   // [nj][mi]
  #pragma unroll
  for (int nj = 0; nj < 4; ++nj)
    #pragma unroll
    for (int mi = 0; mi < 4; ++mi) pacc[nj][mi] = zero4;

  short8 wf0 = pf0, wf1 = pf1, wf2 = pf2, wf3 = pf3;
  #pragma unroll
  for (int ks = 0; ks < 8; ++ks) {
    short8 n0, n1, n2, n3;
    if (ks < 7) {
      n0 = *(const short8*)(wpb + (ks + 1) * 32);
      n1 = *(const short8*)(wpb + 4096 + (ks + 1) * 32);
      n2 = *(const short8*)(wpb + 8192 + (ks + 1) * 32);
      n3 = *(const short8*)(wpb + 12288 + (ks + 1) * 32);
    }
    #pragma unroll
    for (int mi = 0; mi < 4; ++mi) {
      short8 af = *(const short8*)&lds[XS + (mi * 16 + c) * XLD + ks * 32 + g * 8];
      pacc[0][mi] = MFMA16(af, wf0, pacc[0][mi]);
      pacc[1][mi] = MFMA16(af, wf1, pacc[1][mi]);
      pacc[2][mi] = MFMA16(af, wf2, pacc[2][mi]);
      pacc[3][mi] = MFMA16(af, wf3, pacc[3][mi]);
    }
    if (ks < 7) { wf0 = n0; wf1 = n1; wf2 = n2; wf3 = n3; }
  }
  #pragma unroll
  for (int nj = 0; nj < 4; ++nj) {
    const float pb = proj_b[wv * 64 + nj * 16 + c];
    #pragma unroll
    for (int mi = 0; mi < 4; ++mi) {
      #pragma unroll
      for (int r = 0; r < 4; ++r) {
        const int row = mi * 16 + g * 4 + r;
        if (row < 49)
          out[((size_t)b * 49 + row) * 256 + wv * 64 + nj * 16 + c] = pacc[nj][mi][r] + pb;
      }
    }
  }
}

extern "C" void kernel_launch(void* const* d_in, const int* in_sizes, int n_in,
                              void* d_out, int out_size, void* d_ws, size_t ws_size,
                              hipStream_t stream) {
  const float* x          = (const float*)d_in[0];
  const float* mask       = (const float*)d_in[1];
  const float* qkv_w      = (const float*)d_in[2];
  const float* qkv_b      = (const float*)d_in[3];
  const float* proj_w     = (const float*)d_in[4];
  const float* proj_b     = (const float*)d_in[5];
  const float* bias_table = (const float*)d_in[6];
  const int*   rel_index  = (const int*)d_in[7];
  float* out = (float*)d_out;

  unsigned short* wq = (unsigned short*)d_ws;            // 768*256 bf16
  unsigned short* wp = wq + 768 * 256;                   // 256*256 bf16
  float* comb3 = (float*)(wp + 256 * 256);               // 64*4*64*64 f32 (~4 MB)

  prep_wqkv<<<768, 256, 0, stream>>>(qkv_w, wq);
  prep_wproj<<<256, 256, 0, stream>>>(proj_w, wp);
  prep_comb3<<<4096, 256, 0, stream>>>(mask, bias_table, rel_index, comb3);
  win_attn<<<4096, 256, 0, stream>>>(x, qkv_b, proj_b, wq, wp, comb3, out);
}

// Round 12
// 337.445 us; speedup vs baseline: 1.3868x; 1.0278x over previous
//
#include <hip/hip_runtime.h>

typedef __attribute__((ext_vector_type(8))) short short8;
typedef __attribute__((ext_vector_type(4))) float f32x4;

#define MFMA16(a, b, c) __builtin_amdgcn_mfma_f32_16x16x32_bf16((a), (b), (c), 0, 0, 0)

// raw barrier: LDS visibility only (lgkmcnt), leaves global prefetches (vmcnt) in flight
#define BAR() do { asm volatile("s_waitcnt lgkmcnt(0)" ::: "memory"); \
                   __builtin_amdgcn_s_barrier(); \
                   asm volatile("" ::: "memory"); } while (0)

template<int CTRL>
__device__ __forceinline__ float dpp_ror(float x) {
  return __builtin_bit_cast(float,
      __builtin_amdgcn_update_dpp(0, __builtin_bit_cast(int, x), CTRL, 0xF, 0xF, false));
}

__device__ __forceinline__ unsigned cvtpk(float lo, float hi) {
  unsigned r;
  asm("v_cvt_pk_bf16_f32 %0, %1, %2" : "=v"(r) : "v"(lo), "v"(hi));
  return r;
}

__device__ __forceinline__ unsigned short f2b(float f) {
  union { float f; unsigned u; } v; v.f = f;
  return (unsigned short)((v.u + 0x7FFFu + ((v.u >> 16) & 1u)) >> 16);  // RNE
}

// ---------------- prep kernels ----------------
// wqkvT[wcol][k] = bf16(qkv_w[k][wcol]) with SCALE folded into Q columns (wcol<256)
__global__ void prep_wqkv(const float* __restrict__ qkv_w, unsigned short* __restrict__ wq) {
  int idx = blockIdx.x * 256 + threadIdx.x;   // 768*256
  int wcol = idx >> 8, k = idx & 255;
  float v = qkv_w[k * 768 + wcol];
  if (wcol < 256) v *= 0.125f;
  wq[idx] = f2b(v);
}

__global__ void prep_wproj(const float* __restrict__ proj_w, unsigned short* __restrict__ wp) {
  int idx = blockIdx.x * 256 + threadIdx.x;   // 256*256
  int col = idx >> 8, k = idx & 255;
  wp[idx] = f2b(proj_w[k * 256 + col]);
}

// comb3[w][h][j=key][i=query] f32: loads as f32x4 straight into the S accumulator.
__global__ void prep_comb3(const float* __restrict__ mask, const float* __restrict__ bias_table,
                           const int* __restrict__ rel_index, float* __restrict__ comb3) {
  int idx = blockIdx.x * 256 + threadIdx.x;   // 64*4*64*64 = 1048576
  int i = idx & 63, j = (idx >> 6) & 63, h = (idx >> 12) & 3, w = idx >> 14;
  float v;
  if (j >= 49) v = -1e30f;
  else if (i >= 49) v = 0.f;
  else v = mask[(w * 49 + i) * 49 + j] + bias_table[rel_index[i * 49 + j] * 4 + h];
  comb3[idx] = v;
}

// ---------------- fused window-attention kernel ----------------
// LDS layout (ushort units). Padded row strides (stride%32 dwords == 4 -> 2-way only).
#define XS   0        // [64][264]  x staged as bf16; later aliased by attention output O
#define XLD  264
#define QS   16896    // [64][72]   Q (rows=token, cols=dim, scaled)
#define KS   21504    // [64][72]   K
#define VT   26112    // [64][72]   V transposed: [dim][token]
#define PS   30720    // [64][72]   P (softmax probs), per-wave row slices
#define SLD  72
#define LDS_TOT 35328 // ushorts = 70656 B -> 2 blocks/CU

__global__ __launch_bounds__(256, 2) void win_attn(
    const float* __restrict__ x, const float* __restrict__ qkv_b,
    const float* __restrict__ proj_b, const unsigned short* __restrict__ wq,
    const unsigned short* __restrict__ wp, const float* __restrict__ comb3,
    float* __restrict__ out)
{
  __shared__ alignas(16) unsigned short lds[LDS_TOT];
  const int b = blockIdx.x, tid = threadIdx.x;
  const int wv = tid >> 6, l = tid & 63, g = l >> 4, c = l & 15;

  // ---- Phase A: issue ALL x loads first (single latency wait), then convert ----
  f32x4 xv[16];
  {
    const f32x4* xb = (const f32x4*)(x + (size_t)b * (49 * 256));
    #pragma unroll
    for (int it = 0; it < 16; ++it) {
      int idx = tid + it * 256, row = idx >> 6, c4 = idx & 63;
      f32x4 z = {0.f, 0.f, 0.f, 0.f};
      xv[it] = z;
      if (row < 49) xv[it] = xb[row * 64 + c4];
    }
  }
  #pragma unroll
  for (int it = 0; it < 16; ++it) {
    int idx = tid + it * 256, row = idx >> 6, c4 = idx & 63;
    uint2 pk = make_uint2(cvtpk(xv[it].x, xv[it].y), cvtpk(xv[it].z, xv[it].w));
    *(uint2*)&lds[XS + row * XLD + c4 * 4] = pk;
  }
  BAR();

  f32x4 zero4 = {0.f, 0.f, 0.f, 0.f};
  f32x4 oacc[4][4];
  #pragma unroll
  for (int h = 0; h < 4; ++h)
    #pragma unroll
    for (int nd = 0; nd < 4; ++nd) oacc[h][nd] = zero4;

  #pragma unroll
  for (int h = 0; h < 4; ++h) {
    // ---- comb3 prefetch: issued ~B1-duration ahead of B2, straight into S acc ----
    const float* cb3 = comb3 + (((size_t)(b & 63)) * 4 + h) * 4096;
    f32x4 sacc[4];
    #pragma unroll
    for (int ni = 0; ni < 4; ++ni)
      sacc[ni] = *(const f32x4*)(cb3 + (ni * 16 + c) * 64 + wv * 16 + g * 4);

    // ---- B1: QKV GEMM, merged-dst + 2-deep weight lookahead (phase-local) ----
    f32x4 acc[3][4];
    #pragma unroll
    for (int dst = 0; dst < 3; ++dst)
      #pragma unroll
      for (int mi = 0; mi < 4; ++mi) acc[dst][mi] = zero4;

    const unsigned short* wbase = wq + ((size_t)(h * 64 + wv * 16 + c)) * 256 + g * 8;
    short8 wA0 = *(const short8*)(wbase);
    short8 wA1 = *(const short8*)(wbase + 65536);
    short8 wA2 = *(const short8*)(wbase + 131072);
    short8 wB0 = *(const short8*)(wbase + 32);
    short8 wB1 = *(const short8*)(wbase + 65536 + 32);
    short8 wB2 = *(const short8*)(wbase + 131072 + 32);
    #pragma unroll
    for (int ks = 0; ks < 8; ++ks) {
      short8 t0, t1, t2;
      if (ks < 6) {
        t0 = *(const short8*)(wbase + (ks + 2) * 32);
        t1 = *(const short8*)(wbase + 65536 + (ks + 2) * 32);
        t2 = *(const short8*)(wbase + 131072 + (ks + 2) * 32);
      }
      #pragma unroll
      for (int mi = 0; mi < 4; ++mi) {
        short8 af = *(const short8*)&lds[XS + (mi * 16 + c) * XLD + ks * 32 + g * 8];
        acc[0][mi] = MFMA16(af, wA0, acc[0][mi]);
        acc[1][mi] = MFMA16(af, wA1, acc[1][mi]);
        acc[2][mi] = MFMA16(af, wA2, acc[2][mi]);
      }
      wA0 = wB0; wA1 = wB1; wA2 = wB2;
      if (ks < 6) { wB0 = t0; wB1 = t1; wB2 = t2; }
    }
    const float bq = qkv_b[h * 64 + wv * 16 + c] * 0.125f;   // SCALE folded into Q path
    const float bk = qkv_b[256 + h * 64 + wv * 16 + c];
    const float bv = qkv_b[512 + h * 64 + wv * 16 + c];
    const int d = wv * 16 + c;
    #pragma unroll
    for (int mi = 0; mi < 4; ++mi) {
      const int row0 = mi * 16 + g * 4;
      unsigned q01 = cvtpk(acc[0][mi][0] + bq, acc[0][mi][1] + bq);
      unsigned q23 = cvtpk(acc[0][mi][2] + bq, acc[0][mi][3] + bq);
      lds[QS + (row0 + 0) * SLD + d] = (unsigned short)q01;
      lds[QS + (row0 + 1) * SLD + d] = (unsigned short)(q01 >> 16);
      lds[QS + (row0 + 2) * SLD + d] = (unsigned short)q23;
      lds[QS + (row0 + 3) * SLD + d] = (unsigned short)(q23 >> 16);
      unsigned k01 = cvtpk(acc[1][mi][0] + bk, acc[1][mi][1] + bk);
      unsigned k23 = cvtpk(acc[1][mi][2] + bk, acc[1][mi][3] + bk);
      lds[KS + (row0 + 0) * SLD + d] = (unsigned short)k01;
      lds[KS + (row0 + 1) * SLD + d] = (unsigned short)(k01 >> 16);
      lds[KS + (row0 + 2) * SLD + d] = (unsigned short)k23;
      lds[KS + (row0 + 3) * SLD + d] = (unsigned short)(k23 >> 16);
      unsigned v01 = cvtpk(acc[2][mi][0] + bv, acc[2][mi][1] + bv);
      unsigned v23 = cvtpk(acc[2][mi][2] + bv, acc[2][mi][3] + bv);
      *(uint2*)&lds[VT + d * SLD + row0] = make_uint2(v01, v23);   // V transposed, b64
    }
    BAR();

    // ---- B2: S = comb3 + Q K^T (accumulator pre-loaded) ----
    #pragma unroll
    for (int kk = 0; kk < 2; ++kk) {
      short8 af = *(const short8*)&lds[QS + (wv * 16 + c) * SLD + kk * 32 + g * 8];
      #pragma unroll
      for (int ni = 0; ni < 4; ++ni) {
        short8 bf = *(const short8*)&lds[KS + (ni * 16 + c) * SLD + kk * 32 + g * 8];
        sacc[ni] = MFMA16(af, bf, sacc[ni]);
      }
    }

    // ---- B3: row softmax (16-lane DPP rotate-reduce), P -> LDS ----
    #pragma unroll
    for (int r = 0; r < 4; ++r) {
      float m = fmaxf(fmaxf(sacc[0][r], sacc[1][r]), fmaxf(sacc[2][r], sacc[3][r]));
      m = fmaxf(m, dpp_ror<0x128>(m));
      m = fmaxf(m, dpp_ror<0x124>(m));
      m = fmaxf(m, dpp_ror<0x122>(m));
      m = fmaxf(m, dpp_ror<0x121>(m));
      float p[4], s;
      p[0] = __expf(sacc[0][r] - m); p[1] = __expf(sacc[1][r] - m);
      p[2] = __expf(sacc[2][r] - m); p[3] = __expf(sacc[3][r] - m);
      s = (p[0] + p[1]) + (p[2] + p[3]);
      s += dpp_ror<0x128>(s);
      s += dpp_ror<0x124>(s);
      s += dpp_ror<0x122>(s);
      s += dpp_ror<0x121>(s);
      const float inv = 1.0f / s;
      const int row = wv * 16 + g * 4 + r;
      #pragma unroll
      for (int ni = 0; ni < 4; ++ni)
        lds[PS + row * SLD + ni * 16 + c] = f2b(p[ni] * inv);
    }

    // ---- B4: O_h = P V (accumulate per-head in regs) ----
    #pragma unroll
    for (int kk = 0; kk < 2; ++kk) {
      short8 af = *(const short8*)&lds[PS + (wv * 16 + c) * SLD + kk * 32 + g * 8];
      #pragma unroll
      for (int nd = 0; nd < 4; ++nd) {
        short8 bf = *(const short8*)&lds[VT + (nd * 16 + c) * SLD + kk * 32 + g * 8];
        oacc[h][nd] = MFMA16(af, bf, oacc[h][nd]);
      }
    }
    BAR();   // protect QS/KS/VT before next head overwrites
  }

  // ---- Phase D weight prefetch (ks=0,1), issued before the phase-C LDS writes ----
  const unsigned short* wpb = wp + ((size_t)(wv * 64 + c)) * 256 + g * 8;
  short8 pA0 = *(const short8*)(wpb);
  short8 pA1 = *(const short8*)(wpb + 4096);
  short8 pA2 = *(const short8*)(wpb + 8192);
  short8 pA3 = *(const short8*)(wpb + 12288);
  short8 pB0 = *(const short8*)(wpb + 32);
  short8 pB1 = *(const short8*)(wpb + 4096 + 32);
  short8 pB2 = *(const short8*)(wpb + 8192 + 32);
  short8 pB3 = *(const short8*)(wpb + 12288 + 32);

  // ---- Phase C: write O bf16 into XS region (x is dead now), cvtpk packed ----
  #pragma unroll
  for (int h = 0; h < 4; ++h)
    #pragma unroll
    for (int nd = 0; nd < 4; ++nd) {
      const int colc = h * 64 + nd * 16 + c, row0 = wv * 16 + g * 4;
      unsigned o01 = cvtpk(oacc[h][nd][0], oacc[h][nd][1]);
      unsigned o23 = cvtpk(oacc[h][nd][2], oacc[h][nd][3]);
      lds[XS + (row0 + 0) * XLD + colc] = (unsigned short)o01;
      lds[XS + (row0 + 1) * XLD + colc] = (unsigned short)(o01 >> 16);
      lds[XS + (row0 + 2) * XLD + colc] = (unsigned short)o23;
      lds[XS + (row0 + 3) * XLD + colc] = (unsigned short)(o23 >> 16);
    }
  BAR();

  // ---- Phase D: out = O @ proj_w + proj_b, k-outer, 2-deep lookahead ----
  f32x4 pacc[4][4];   // [nj][mi]
  #pragma unroll
  for (int nj = 0; nj < 4; ++nj)
    #pragma unroll
    for (int mi = 0; mi < 4; ++mi) pacc[nj][mi] = zero4;

  #pragma unroll
  for (int ks = 0; ks < 8; ++ks) {
    short8 t0, t1, t2, t3;
    if (ks < 6) {
      t0 = *(const short8*)(wpb + (ks + 2) * 32);
      t1 = *(const short8*)(wpb + 4096 + (ks + 2) * 32);
      t2 = *(const short8*)(wpb + 8192 + (ks + 2) * 32);
      t3 = *(const short8*)(wpb + 12288 + (ks + 2) * 32);
    }
    #pragma unroll
    for (int mi = 0; mi < 4; ++mi) {
      short8 af = *(const short8*)&lds[XS + (mi * 16 + c) * XLD + ks * 32 + g * 8];
      pacc[0][mi] = MFMA16(af, pA0, pacc[0][mi]);
      pacc[1][mi] = MFMA16(af, pA1, pacc[1][mi]);
      pacc[2][mi] = MFMA16(af, pA2, pacc[2][mi]);
      pacc[3][mi] = MFMA16(af, pA3, pacc[3][mi]);
    }
    pA0 = pB0; pA1 = pB1; pA2 = pB2; pA3 = pB3;
    if (ks < 6) { pB0 = t0; pB1 = t1; pB2 = t2; pB3 = t3; }
  }
  #pragma unroll
  for (int nj = 0; nj < 4; ++nj) {
    const float pb = proj_b[wv * 64 + nj * 16 + c];
    #pragma unroll
    for (int mi = 0; mi < 4; ++mi) {
      #pragma unroll
      for (int r = 0; r < 4; ++r) {
        const int row = mi * 16 + g * 4 + r;
        if (row < 49)
          out[((size_t)b * 49 + row) * 256 + wv * 64 + nj * 16 + c] = pacc[nj][mi][r] + pb;
      }
    }
  }
}

extern "C" void kernel_launch(void* const* d_in, const int* in_sizes, int n_in,
                              void* d_out, int out_size, void* d_ws, size_t ws_size,
                              hipStream_t stream) {
  const float* x          = (const float*)d_in[0];
  const float* mask       = (const float*)d_in[1];
  const float* qkv_w      = (const float*)d_in[2];
  const float* qkv_b      = (const float*)d_in[3];
  const float* proj_w     = (const float*)d_in[4];
  const float* proj_b     = (const float*)d_in[5];
  const float* bias_table = (const float*)d_in[6];
  const int*   rel_index  = (const int*)d_in[7];
  float* out = (float*)d_out;

  unsigned short* wq = (unsigned short*)d_ws;            // 768*256 bf16
  unsigned short* wp = wq + 768 * 256;                   // 256*256 bf16
  float* comb3 = (float*)(wp + 256 * 256);               // 64*4*64*64 f32 (~4 MB)

  prep_wqkv<<<768, 256, 0, stream>>>(qkv_w, wq);
  prep_wproj<<<256, 256, 0, stream>>>(proj_w, wp);
  prep_comb3<<<4096, 256, 0, stream>>>(mask, bias_table, rel_index, comb3);
  win_attn<<<4096, 256, 0, stream>>>(x, qkv_b, proj_b, wq, wp, comb3, out);
}

// Round 13
// 331.718 us; speedup vs baseline: 1.4107x; 1.0173x over previous
//
#include <hip/hip_runtime.h>

typedef __attribute__((ext_vector_type(8))) short short8;
typedef __attribute__((ext_vector_type(4))) float f32x4;

#define MFMA16(a, b, c) __builtin_amdgcn_mfma_f32_16x16x32_bf16((a), (b), (c), 0, 0, 0)

// raw barrier: LDS visibility only (lgkmcnt), leaves global prefetches (vmcnt) in flight
#define BAR() do { asm volatile("s_waitcnt lgkmcnt(0)" ::: "memory"); \
                   __builtin_amdgcn_s_barrier(); \
                   asm volatile("" ::: "memory"); } while (0)

template<int CTRL>
__device__ __forceinline__ float dpp_ror(float x) {
  return __builtin_bit_cast(float,
      __builtin_amdgcn_update_dpp(0, __builtin_bit_cast(int, x), CTRL, 0xF, 0xF, false));
}

__device__ __forceinline__ unsigned cvtpk(float lo, float hi) {
  unsigned r;
  asm("v_cvt_pk_bf16_f32 %0, %1, %2" : "=v"(r) : "v"(lo), "v"(hi));
  return r;
}

__device__ __forceinline__ unsigned short f2b(float f) {
  union { float f; unsigned u; } v; v.f = f;
  return (unsigned short)((v.u + 0x7FFFu + ((v.u >> 16) & 1u)) >> 16);  // RNE
}

// ---------------- prep kernels ----------------
// wqkvT[wcol][k] = bf16(qkv_w[k][wcol]) with SCALE folded into Q columns (wcol<256)
__global__ void prep_wqkv(const float* __restrict__ qkv_w, unsigned short* __restrict__ wq) {
  int idx = blockIdx.x * 256 + threadIdx.x;   // 768*256
  int wcol = idx >> 8, k = idx & 255;
  float v = qkv_w[k * 768 + wcol];
  if (wcol < 256) v *= 0.125f;
  wq[idx] = f2b(v);
}

__global__ void prep_wproj(const float* __restrict__ proj_w, unsigned short* __restrict__ wp) {
  int idx = blockIdx.x * 256 + threadIdx.x;   // 256*256
  int col = idx >> 8, k = idx & 255;
  wp[idx] = f2b(proj_w[k * 256 + col]);
}

// comb3[w][h][j=key][i=query] f32: loads as f32x4 straight into the S accumulator.
__global__ void prep_comb3(const float* __restrict__ mask, const float* __restrict__ bias_table,
                           const int* __restrict__ rel_index, float* __restrict__ comb3) {
  int idx = blockIdx.x * 256 + threadIdx.x;   // 64*4*64*64 = 1048576
  int i = idx & 63, j = (idx >> 6) & 63, h = (idx >> 12) & 3, w = idx >> 14;
  float v;
  if (j >= 49) v = -1e30f;
  else if (i >= 49) v = 0.f;
  else v = mask[(w * 49 + i) * 49 + j] + bias_table[rel_index[i * 49 + j] * 4 + h];
  comb3[idx] = v;
}

// ---------------- fused window-attention kernel ----------------
// LDS (ushort units), padded strides (no swizzle). 53,504 B -> 3 blocks/CU.
// Rows 49-63 of each tile are row-48 duplicates (XR broadcast), neutralized by
// comb3's -1e30 key mask and row-validity at the writes (R3-proven).
#define XS   0        // [48][264]  x bf16 rows 0-47; later O rows 0-47
#define XLD  264
#define XR   12672    // [256]      x row 48; later O row 48
#define QPS  12928    // [64][72]   Q, later aliased by P (per-wave row slices)
#define KS   17536    // [64][72]   K
#define VT   22144    // [64][72]   V transposed: [dim][token]
#define SLD  72
#define LDS_TOT 26752 // ushorts = 53,504 B

__global__ __launch_bounds__(256, 3) void win_attn(
    const float* __restrict__ x, const float* __restrict__ qkv_b,
    const float* __restrict__ proj_b, const unsigned short* __restrict__ wq,
    const unsigned short* __restrict__ wp, const float* __restrict__ comb3,
    float* __restrict__ out)
{
  __shared__ alignas(16) unsigned short lds[LDS_TOT];
  const int b = blockIdx.x, tid = threadIdx.x;
  const int wv = tid >> 6, l = tid & 63, g = l >> 4, c = l & 15;

  // ---- Phase A: batch-issue ALL x loads, then convert. Rows 0-47 -> XS, row 48 -> XR ----
  {
    const f32x4* xb = (const f32x4*)(x + (size_t)b * (49 * 256));
    f32x4 xv[12];
    #pragma unroll
    for (int it = 0; it < 6; ++it) {
      int idx = tid + it * 256, row = idx >> 5, c8 = idx & 31;   // rows 0..47
      const f32x4* p = xb + row * 64 + c8 * 2;
      xv[2 * it] = p[0]; xv[2 * it + 1] = p[1];
    }
    f32x4 xr0, xr1;
    if (tid < 32) { const f32x4* p = xb + 48 * 64 + tid * 2; xr0 = p[0]; xr1 = p[1]; }
    #pragma unroll
    for (int it = 0; it < 6; ++it) {
      int idx = tid + it * 256, row = idx >> 5, c8 = idx & 31;
      uint4 pk = make_uint4(cvtpk(xv[2 * it].x, xv[2 * it].y),
                            cvtpk(xv[2 * it].z, xv[2 * it].w),
                            cvtpk(xv[2 * it + 1].x, xv[2 * it + 1].y),
                            cvtpk(xv[2 * it + 1].z, xv[2 * it + 1].w));
      *(uint4*)&lds[XS + row * XLD + c8 * 8] = pk;
    }
    if (tid < 32) {
      uint4 pk = make_uint4(cvtpk(xr0.x, xr0.y), cvtpk(xr0.z, xr0.w),
                            cvtpk(xr1.x, xr1.y), cvtpk(xr1.z, xr1.w));
      *(uint4*)&lds[XR + tid * 8] = pk;
    }
  }
  BAR();

  f32x4 zero4 = {0.f, 0.f, 0.f, 0.f};
  f32x4 oacc[4][4];
  #pragma unroll
  for (int h = 0; h < 4; ++h)
    #pragma unroll
    for (int nd = 0; nd < 4; ++nd) oacc[h][nd] = zero4;

  #pragma unroll
  for (int h = 0; h < 4; ++h) {
    // ---- comb3 prefetch (phase-local): issued ~B1-duration ahead, straight into S acc ----
    const float* cb3 = comb3 + (((size_t)(b & 63)) * 4 + h) * 4096;
    f32x4 sacc[4];
    #pragma unroll
    for (int ni = 0; ni < 4; ++ni)
      sacc[ni] = *(const f32x4*)(cb3 + (ni * 16 + c) * 64 + wv * 16 + g * 4);

    // ---- B1: QKV GEMM, merged-dst + 2-deep weight lookahead (phase-local) ----
    f32x4 acc[3][4];
    #pragma unroll
    for (int dst = 0; dst < 3; ++dst)
      #pragma unroll
      for (int mi = 0; mi < 4; ++mi) acc[dst][mi] = zero4;

    const unsigned short* wbase = wq + ((size_t)(h * 64 + wv * 16 + c)) * 256 + g * 8;
    short8 wA0 = *(const short8*)(wbase);
    short8 wA1 = *(const short8*)(wbase + 65536);
    short8 wA2 = *(const short8*)(wbase + 131072);
    short8 wB0 = *(const short8*)(wbase + 32);
    short8 wB1 = *(const short8*)(wbase + 65536 + 32);
    short8 wB2 = *(const short8*)(wbase + 131072 + 32);
    #pragma unroll
    for (int ks = 0; ks < 8; ++ks) {
      short8 t0, t1, t2;
      if (ks < 6) {
        t0 = *(const short8*)(wbase + (ks + 2) * 32);
        t1 = *(const short8*)(wbase + 65536 + (ks + 2) * 32);
        t2 = *(const short8*)(wbase + 131072 + (ks + 2) * 32);
      }
      #pragma unroll
      for (int mi = 0; mi < 3; ++mi) {
        short8 af = *(const short8*)&lds[XS + (mi * 16 + c) * XLD + ks * 32 + g * 8];
        acc[0][mi] = MFMA16(af, wA0, acc[0][mi]);
        acc[1][mi] = MFMA16(af, wA1, acc[1][mi]);
        acc[2][mi] = MFMA16(af, wA2, acc[2][mi]);
      }
      short8 a3 = *(const short8*)&lds[XR + ks * 32 + g * 8];   // broadcast row 48
      acc[0][3] = MFMA16(a3, wA0, acc[0][3]);
      acc[1][3] = MFMA16(a3, wA1, acc[1][3]);
      acc[2][3] = MFMA16(a3, wA2, acc[2][3]);
      wA0 = wB0; wA1 = wB1; wA2 = wB2;
      if (ks < 6) { wB0 = t0; wB1 = t1; wB2 = t2; }
    }
    const float bq = qkv_b[h * 64 + wv * 16 + c] * 0.125f;   // SCALE folded into Q path
    const float bk = qkv_b[256 + h * 64 + wv * 16 + c];
    const float bv = qkv_b[512 + h * 64 + wv * 16 + c];
    const int d = wv * 16 + c;
    #pragma unroll
    for (int mi = 0; mi < 4; ++mi) {
      const int row0 = mi * 16 + g * 4;
      unsigned q01 = cvtpk(acc[0][mi][0] + bq, acc[0][mi][1] + bq);
      unsigned q23 = cvtpk(acc[0][mi][2] + bq, acc[0][mi][3] + bq);
      lds[QPS + (row0 + 0) * SLD + d] = (unsigned short)q01;
      lds[QPS + (row0 + 1) * SLD + d] = (unsigned short)(q01 >> 16);
      lds[QPS + (row0 + 2) * SLD + d] = (unsigned short)q23;
      lds[QPS + (row0 + 3) * SLD + d] = (unsigned short)(q23 >> 16);
      unsigned k01 = cvtpk(acc[1][mi][0] + bk, acc[1][mi][1] + bk);
      unsigned k23 = cvtpk(acc[1][mi][2] + bk, acc[1][mi][3] + bk);
      lds[KS + (row0 + 0) * SLD + d] = (unsigned short)k01;
      lds[KS + (row0 + 1) * SLD + d] = (unsigned short)(k01 >> 16);
      lds[KS + (row0 + 2) * SLD + d] = (unsigned short)k23;
      lds[KS + (row0 + 3) * SLD + d] = (unsigned short)(k23 >> 16);
      unsigned v01 = cvtpk(acc[2][mi][0] + bv, acc[2][mi][1] + bv);
      unsigned v23 = cvtpk(acc[2][mi][2] + bv, acc[2][mi][3] + bv);
      *(uint2*)&lds[VT + d * SLD + row0] = make_uint2(v01, v23);   // V transposed, b64
    }
    BAR();

    // ---- B2: S = comb3 + Q K^T (accumulator pre-loaded) ----
    #pragma unroll
    for (int kk = 0; kk < 2; ++kk) {
      short8 af = *(const short8*)&lds[QPS + (wv * 16 + c) * SLD + kk * 32 + g * 8];
      #pragma unroll
      for (int ni = 0; ni < 4; ++ni) {
        short8 bf = *(const short8*)&lds[KS + (ni * 16 + c) * SLD + kk * 32 + g * 8];
        sacc[ni] = MFMA16(af, bf, sacc[ni]);
      }
    }

    // ---- B3: row softmax (16-lane DPP rotate-reduce), P -> QPS (aliases Q, own rows) ----
    #pragma unroll
    for (int r = 0; r < 4; ++r) {
      float m = fmaxf(fmaxf(sacc[0][r], sacc[1][r]), fmaxf(sacc[2][r], sacc[3][r]));
      m = fmaxf(m, dpp_ror<0x128>(m));
      m = fmaxf(m, dpp_ror<0x124>(m));
      m = fmaxf(m, dpp_ror<0x122>(m));
      m = fmaxf(m, dpp_ror<0x121>(m));
      float p[4], s;
      p[0] = __expf(sacc[0][r] - m); p[1] = __expf(sacc[1][r] - m);
      p[2] = __expf(sacc[2][r] - m); p[3] = __expf(sacc[3][r] - m);
      s = (p[0] + p[1]) + (p[2] + p[3]);
      s += dpp_ror<0x128>(s);
      s += dpp_ror<0x124>(s);
      s += dpp_ror<0x122>(s);
      s += dpp_ror<0x121>(s);
      const float inv = 1.0f / s;
      const int row = wv * 16 + g * 4 + r;
      unsigned p01 = cvtpk(p[0] * inv, p[1] * inv);
      unsigned p23 = cvtpk(p[2] * inv, p[3] * inv);
      lds[QPS + row * SLD +  0 + c] = (unsigned short)p01;
      lds[QPS + row * SLD + 16 + c] = (unsigned short)(p01 >> 16);
      lds[QPS + row * SLD + 32 + c] = (unsigned short)p23;
      lds[QPS + row * SLD + 48 + c] = (unsigned short)(p23 >> 16);
    }

    // ---- B4: O_h = P V (accumulate per-head in regs) ----
    #pragma unroll
    for (int kk = 0; kk < 2; ++kk) {
      short8 af = *(const short8*)&lds[QPS + (wv * 16 + c) * SLD + kk * 32 + g * 8];
      #pragma unroll
      for (int nd = 0; nd < 4; ++nd) {
        short8 bf = *(const short8*)&lds[VT + (nd * 16 + c) * SLD + kk * 32 + g * 8];
        oacc[h][nd] = MFMA16(af, bf, oacc[h][nd]);
      }
    }
    BAR();   // protect QPS/KS/VT before next head overwrites
  }

  // ---- Phase D weight prefetch (ks=0,1), issued before the phase-C LDS writes ----
  const unsigned short* wpb = wp + ((size_t)(wv * 64 + c)) * 256 + g * 8;
  short8 pA0 = *(const short8*)(wpb);
  short8 pA1 = *(const short8*)(wpb + 4096);
  short8 pA2 = *(const short8*)(wpb + 8192);
  short8 pA3 = *(const short8*)(wpb + 12288);
  short8 pB0 = *(const short8*)(wpb + 32);
  short8 pB1 = *(const short8*)(wpb + 4096 + 32);
  short8 pB2 = *(const short8*)(wpb + 8192 + 32);
  short8 pB3 = *(const short8*)(wpb + 12288 + 32);

  // ---- Phase C: O bf16 -> XS rows 0-47 (waves 0-2) + XR row 48 (wave 3, g==0) ----
  if (wv < 3) {
    #pragma unroll
    for (int h = 0; h < 4; ++h)
      #pragma unroll
      for (int nd = 0; nd < 4; ++nd) {
        const int colc = h * 64 + nd * 16 + c, row0 = wv * 16 + g * 4;
        unsigned o01 = cvtpk(oacc[h][nd][0], oacc[h][nd][1]);
        unsigned o23 = cvtpk(oacc[h][nd][2], oacc[h][nd][3]);
        lds[XS + (row0 + 0) * XLD + colc] = (unsigned short)o01;
        lds[XS + (row0 + 1) * XLD + colc] = (unsigned short)(o01 >> 16);
        lds[XS + (row0 + 2) * XLD + colc] = (unsigned short)o23;
        lds[XS + (row0 + 3) * XLD + colc] = (unsigned short)(o23 >> 16);
      }
  } else if (g == 0) {   // wave 3 holds rows 48-63; only row 48 (g==0, r==0) is real
    #pragma unroll
    for (int h = 0; h < 4; ++h)
      #pragma unroll
      for (int nd = 0; nd < 4; ++nd)
        lds[XR + h * 64 + nd * 16 + c] =
            (unsigned short)cvtpk(oacc[h][nd][0], oacc[h][nd][0]);
  }
  BAR();

  // ---- Phase D: out = O @ proj_w + proj_b, k-outer, 2-deep lookahead ----
  f32x4 pacc[4][4];   // [nj][mi]
  #pragma unroll
  for (int nj = 0; nj < 4; ++nj)
    #pragma unroll
    for (int mi = 0; mi < 4; ++mi) pacc[nj][mi] = zero4;

  #pragma unroll
  for (int ks = 0; ks < 8; ++ks) {
    short8 t0, t1, t2, t3;
    if (ks < 6) {
      t0 = *(const short8*)(wpb + (ks + 2) * 32);
      t1 = *(const short8*)(wpb + 4096 + (ks + 2) * 32);
      t2 = *(const short8*)(wpb + 8192 + (ks + 2) * 32);
      t3 = *(const short8*)(wpb + 12288 + (ks + 2) * 32);
    }
    #pragma unroll
    for (int mi = 0; mi < 3; ++mi) {
      short8 af = *(const short8*)&lds[XS + (mi * 16 + c) * XLD + ks * 32 + g * 8];
      pacc[0][mi] = MFMA16(af, pA0, pacc[0][mi]);
      pacc[1][mi] = MFMA16(af, pA1, pacc[1][mi]);
      pacc[2][mi] = MFMA16(af, pA2, pacc[2][mi]);
      pacc[3][mi] = MFMA16(af, pA3, pacc[3][mi]);
    }
    short8 a3 = *(const short8*)&lds[XR + ks * 32 + g * 8];   // broadcast O row 48
    pacc[0][3] = MFMA16(a3, pA0, pacc[0][3]);
    pacc[1][3] = MFMA16(a3, pA1, pacc[1][3]);
    pacc[2][3] = MFMA16(a3, pA2, pacc[2][3]);
    pacc[3][3] = MFMA16(a3, pA3, pacc[3][3]);
    pA0 = pB0; pA1 = pB1; pA2 = pB2; pA3 = pB3;
    if (ks < 6) { pB0 = t0; pB1 = t1; pB2 = t2; pB3 = t3; }
  }
  #pragma unroll
  for (int nj = 0; nj < 4; ++nj) {
    const float pb = proj_b[wv * 64 + nj * 16 + c];
    #pragma unroll
    for (int mi = 0; mi < 3; ++mi) {
      #pragma unroll
      for (int r = 0; r < 4; ++r) {
        const int row = mi * 16 + g * 4 + r;   // 0..47, always valid
        out[((size_t)b * 49 + row) * 256 + wv * 64 + nj * 16 + c] = pacc[nj][mi][r] + pb;
      }
    }
    if (g == 0)   // mi=3 tile: only row 48 is real
      out[((size_t)b * 49 + 48) * 256 + wv * 64 + nj * 16 + c] = pacc[nj][3][0] + pb;
  }
}

extern "C" void kernel_launch(void* const* d_in, const int* in_sizes, int n_in,
                              void* d_out, int out_size, void* d_ws, size_t ws_size,
                              hipStream_t stream) {
  const float* x          = (const float*)d_in[0];
  const float* mask       = (const float*)d_in[1];
  const float* qkv_w      = (const float*)d_in[2];
  const float* qkv_b      = (const float*)d_in[3];
  const float* proj_w     = (const float*)d_in[4];
  const float* proj_b     = (const float*)d_in[5];
  const float* bias_table = (const float*)d_in[6];
  const int*   rel_index  = (const int*)d_in[7];
  float* out = (float*)d_out;

  unsigned short* wq = (unsigned short*)d_ws;            // 768*256 bf16
  unsigned short* wp = wq + 768 * 256;                   // 256*256 bf16
  float* comb3 = (float*)(wp + 256 * 256);               // 64*4*64*64 f32 (~4 MB)

  prep_wqkv<<<768, 256, 0, stream>>>(qkv_w, wq);
  prep_wproj<<<256, 256, 0, stream>>>(proj_w, wp);
  prep_comb3<<<4096, 256, 0, stream>>>(mask, bias_table, rel_index, comb3);
  win_attn<<<4096, 256, 0, stream>>>(x, qkv_b, proj_b, wq, wp, comb3, out);
}